// Round 5
// baseline (81.613 us; speedup 1.0000x reference)
//
#include <hip/hip_runtime.h>

// Problem: x [64,1,257,257] f32, conv_w [1,1,2,2], conv_b [1], qparams [2,4].
// Output [64,2,256,256] f32 = concat(conv-relu, qmap) on channel axis.
//
// Analytic collapse (re-derived R2; harness-verified, absmax 0.0625):
//   - qparams provably irrelevant (P*D2*P*D1 tail preserves Z-probabilities).
//   - qmap per 2x2 post-ReLU patch = cos(TL)*cos(TR)*cos(BR).
//
// R5 measured 79.24 us == R2's 78.9 us despite a totally different load path.
// => load path was never the bottleneck. rocprof top-5 = 256 MiB harness
// poison fills at 44.5 us / 75% peak. Theory: score = fill + kernel, and/or
// the fill's dirty-L3 writebacks drain during our kernel (shared floor).
//
// R6 (this round): discriminating experiment + cleanup.
//   - staging addressing simplified: 9 unconditional coalesced row loads
//     (lds[r*LPITCH+tid] = src[r*INW+tid]) + 1 predicated halo column load;
//     removes the div/mod chain of the k-loop entirely.
//   - nontemporal LOADS on x: input is single-pass per block (1-row halo
//     only); don't let it allocate in L2/L3 against the fill's dirty data.
//   - everything else unchanged from the verified R5 kernel.
//   If dur_us stays ~79: harness floor confirmed -> declare ceiling next.

#define BATCH 64
#define INH   257
#define INW   257
#define OH    256
#define OW    256
#define RG    32            // row-groups per image: 8 output rows each
#define LROWS 9             // input rows staged per block
#define LPITCH 264          // LDS row pitch in floats (multiple of 4, padded)

typedef float fvec4 __attribute__((ext_vector_type(4)));

__device__ __forceinline__ void store_nt4(float* p, float x, float y, float z, float w)
{
    fvec4 v; v.x = x; v.y = y; v.z = z; v.w = w;
    __builtin_nontemporal_store(v, (fvec4*)p);
}

__global__ __launch_bounds__(256) void conv_enh_lds(
    const float* __restrict__ x,
    const float* __restrict__ cw,
    const float* __restrict__ cb,
    float* __restrict__ out)
{
    __shared__ float lds[LROWS * LPITCH];   // 9*264*4 = 9504 B

    const int tid = threadIdx.x;
    const int blk = blockIdx.x;
    const int rg  = blk & (RG - 1);          // 0..31 -> input rows 8*rg .. 8*rg+8
    const int b   = blk >> 5;                // 0..63

    // uniform weight/bias loads issued first: latency hides under staging
    const float w00 = cw[0], w01 = cw[1], w10 = cw[2], w11 = cw[3];
    const float bias = cb[0];

    const int r_base = rg * 8;
    const float* __restrict__ src =
        x + (size_t)b * INH * INW + (size_t)r_base * INW;

    // ---- stage: 9 rows x 257 cols; 9 coalesced row loads + 1 halo load ----
    #pragma unroll
    for (int r = 0; r < LROWS; ++r)
        lds[r * LPITCH + tid] = __builtin_nontemporal_load(src + r * INW + tid);
    if (tid < LROWS)
        lds[tid * LPITCH + 256] = __builtin_nontemporal_load(src + tid * INW + 256);
    __syncthreads();

    // one wave = one output row-pair across the full width
    const int j  = tid & 63;                 // 0..63 -> output cols 4j..4j+3
    const int il = tid >> 6;                 // 0..3  -> local row-pair
    const int c0 = 4 * j;

    const float* __restrict__ l0 = &lds[(2 * il) * LPITCH + c0]; // 16B-aligned
    const float* __restrict__ l1 = l0 + LPITCH;
    const float* __restrict__ l2 = l1 + LPITCH;

    const fvec4 A = *(const fvec4*)l0;  const float a4 = l0[4];
    const fvec4 M = *(const fvec4*)l1;  const float m4 = l1[4];
    const fvec4 Z = *(const fvec4*)l2;  const float z4 = l2[4];

    // cross-correlation + bias + ReLU; top row (r0) and bottom row (r0+1)
    const float t0 = fmaxf(fmaf(w11, M.y, fmaf(w10, M.x, fmaf(w01, A.y, fmaf(w00, A.x, bias)))), 0.f);
    const float t1 = fmaxf(fmaf(w11, M.z, fmaf(w10, M.y, fmaf(w01, A.z, fmaf(w00, A.y, bias)))), 0.f);
    const float t2 = fmaxf(fmaf(w11, M.w, fmaf(w10, M.z, fmaf(w01, A.w, fmaf(w00, A.z, bias)))), 0.f);
    const float t3 = fmaxf(fmaf(w11, m4,  fmaf(w10, M.w, fmaf(w01, a4,  fmaf(w00, A.w, bias)))), 0.f);
    const float u0 = fmaxf(fmaf(w11, Z.y, fmaf(w10, Z.x, fmaf(w01, M.y, fmaf(w00, M.x, bias)))), 0.f);
    const float u1 = fmaxf(fmaf(w11, Z.z, fmaf(w10, Z.y, fmaf(w01, M.z, fmaf(w00, M.y, bias)))), 0.f);
    const float u2 = fmaxf(fmaf(w11, Z.w, fmaf(w10, Z.z, fmaf(w01, M.w, fmaf(w00, M.z, bias)))), 0.f);
    const float u3 = fmaxf(fmaf(w11, z4,  fmaf(w10, Z.w, fmaf(w01, m4,  fmaf(w00, M.w, bias)))), 0.f);

    // qmap per 2x2 patch: cos(TL)*cos(TR)*cos(BR)
    const float q0 = __cosf(t0) * __cosf(t1) * __cosf(u1);
    const float q1 = __cosf(t2) * __cosf(t3) * __cosf(u3);

    const int r0 = r_base + 2 * il;
    float* __restrict__ o0 = out + (size_t)b * 2 * OH * OW + (size_t)r0 * OW + c0;
    float* __restrict__ o1 = o0 + OH * OW;

    // out is write-once: non-temporal stores keep L2 for the input overlap
    store_nt4(o0,      t0, t1, t2, t3);
    store_nt4(o0 + OW, u0, u1, u2, u3);
    store_nt4(o1,      q0, q0, q1, q1);
    store_nt4(o1 + OW, q0, q0, q1, q1);
}

extern "C" void kernel_launch(void* const* d_in, const int* in_sizes, int n_in,
                              void* d_out, int out_size, void* d_ws, size_t ws_size,
                              hipStream_t stream)
{
    const float* x  = (const float*)d_in[0];
    const float* cw = (const float*)d_in[1];
    const float* cb = (const float*)d_in[2];
    // d_in[3] (qparams) provably does not affect the output.
    float* out = (float*)d_out;

    const int grid  = BATCH * RG;   // 2048 blocks
    const int block = 256;
    conv_enh_lds<<<grid, block, 0, stream>>>(x, cw, cb, out);
}

// Round 6
// 79.776 us; speedup vs baseline: 1.0230x; 1.0230x over previous
//
#include <hip/hip_runtime.h>

// Problem: x [64,1,257,257] f32, conv_w [1,1,2,2], conv_b [1], qparams [2,4].
// Output [64,2,256,256] f32 = concat(conv-relu, qmap) on channel axis.
//
// Analytic collapse (re-derived R2; harness-verified, absmax 0.0625):
//   - qparams provably irrelevant (P*D2*P*D1 tail preserves Z-probabilities).
//   - qmap per 2x2 post-ReLU patch = cos(TL)*cos(TR)*cos(BR).
//
// Measurement state (R4/R5):
//   - score 79.2 (R5) / 81.6 (R6, nt input loads -> +2.4 regression, reverted
//     here). Top-5 dispatches are all 256 MiB harness poison fills at 43.5 us
//     / 6.17 TB/s; our kernel NEVER appears => its GPU dur < 43.4 us while
//     score is ~79. Score therefore includes harness work (fill + restores).
//   - Kernel true dur is in [~8.5 us traffic floor, 43.4 us]. R2 (amplified
//     loads) == R5 (clean staging) argues the kernel is sub-dominant (M2).
//
// R7 (this round): revert nt INPUT loads (keep L2 for the 1-row halo overlap
//   between adjacent row-group blocks); keep simplified 9-row staging and nt
//   output stores. Expect score back to ~79.2 under both models.
//   Next-round plan if ~79.2 confirmed: x4 idempotent-store diagnostic to
//   surface the kernel's own counters above the fills' 43.5 us threshold.

#define BATCH 64
#define INH   257
#define INW   257
#define OH    256
#define OW    256
#define RG    32            // row-groups per image: 8 output rows each
#define LROWS 9             // input rows staged per block
#define LPITCH 264          // LDS row pitch in floats (multiple of 4, padded)

typedef float fvec4 __attribute__((ext_vector_type(4)));

__device__ __forceinline__ void store_nt4(float* p, float x, float y, float z, float w)
{
    fvec4 v; v.x = x; v.y = y; v.z = z; v.w = w;
    __builtin_nontemporal_store(v, (fvec4*)p);
}

__global__ __launch_bounds__(256) void conv_enh_lds(
    const float* __restrict__ x,
    const float* __restrict__ cw,
    const float* __restrict__ cb,
    float* __restrict__ out)
{
    __shared__ float lds[LROWS * LPITCH];   // 9*264*4 = 9504 B

    const int tid = threadIdx.x;
    const int blk = blockIdx.x;
    const int rg  = blk & (RG - 1);          // 0..31 -> input rows 8*rg .. 8*rg+8
    const int b   = blk >> 5;                // 0..63

    // uniform weight/bias loads issued first: latency hides under staging
    const float w00 = cw[0], w01 = cw[1], w10 = cw[2], w11 = cw[3];
    const float bias = cb[0];

    const int r_base = rg * 8;
    const float* __restrict__ src =
        x + (size_t)b * INH * INW + (size_t)r_base * INW;

    // ---- stage: 9 rows x 257 cols; 9 coalesced row loads + 1 halo load ----
    #pragma unroll
    for (int r = 0; r < LROWS; ++r)
        lds[r * LPITCH + tid] = src[r * INW + tid];
    if (tid < LROWS)
        lds[tid * LPITCH + 256] = src[tid * INW + 256];
    __syncthreads();

    // one wave = one output row-pair across the full width
    const int j  = tid & 63;                 // 0..63 -> output cols 4j..4j+3
    const int il = tid >> 6;                 // 0..3  -> local row-pair
    const int c0 = 4 * j;

    const float* __restrict__ l0 = &lds[(2 * il) * LPITCH + c0]; // 16B-aligned
    const float* __restrict__ l1 = l0 + LPITCH;
    const float* __restrict__ l2 = l1 + LPITCH;

    const fvec4 A = *(const fvec4*)l0;  const float a4 = l0[4];
    const fvec4 M = *(const fvec4*)l1;  const float m4 = l1[4];
    const fvec4 Z = *(const fvec4*)l2;  const float z4 = l2[4];

    // cross-correlation + bias + ReLU; top row (r0) and bottom row (r0+1)
    const float t0 = fmaxf(fmaf(w11, M.y, fmaf(w10, M.x, fmaf(w01, A.y, fmaf(w00, A.x, bias)))), 0.f);
    const float t1 = fmaxf(fmaf(w11, M.z, fmaf(w10, M.y, fmaf(w01, A.z, fmaf(w00, A.y, bias)))), 0.f);
    const float t2 = fmaxf(fmaf(w11, M.w, fmaf(w10, M.z, fmaf(w01, A.w, fmaf(w00, A.z, bias)))), 0.f);
    const float t3 = fmaxf(fmaf(w11, m4,  fmaf(w10, M.w, fmaf(w01, a4,  fmaf(w00, A.w, bias)))), 0.f);
    const float u0 = fmaxf(fmaf(w11, Z.y, fmaf(w10, Z.x, fmaf(w01, M.y, fmaf(w00, M.x, bias)))), 0.f);
    const float u1 = fmaxf(fmaf(w11, Z.z, fmaf(w10, Z.y, fmaf(w01, M.z, fmaf(w00, M.y, bias)))), 0.f);
    const float u2 = fmaxf(fmaf(w11, Z.w, fmaf(w10, Z.z, fmaf(w01, M.w, fmaf(w00, M.z, bias)))), 0.f);
    const float u3 = fmaxf(fmaf(w11, z4,  fmaf(w10, Z.w, fmaf(w01, m4,  fmaf(w00, M.w, bias)))), 0.f);

    // qmap per 2x2 patch: cos(TL)*cos(TR)*cos(BR)
    const float q0 = __cosf(t0) * __cosf(t1) * __cosf(u1);
    const float q1 = __cosf(t2) * __cosf(t3) * __cosf(u3);

    const int r0 = r_base + 2 * il;
    float* __restrict__ o0 = out + (size_t)b * 2 * OH * OW + (size_t)r0 * OW + c0;
    float* __restrict__ o1 = o0 + OH * OW;

    // out is write-once: non-temporal stores keep L2 for the input overlap
    store_nt4(o0,      t0, t1, t2, t3);
    store_nt4(o0 + OW, u0, u1, u2, u3);
    store_nt4(o1,      q0, q0, q1, q1);
    store_nt4(o1 + OW, q0, q0, q1, q1);
}

extern "C" void kernel_launch(void* const* d_in, const int* in_sizes, int n_in,
                              void* d_out, int out_size, void* d_ws, size_t ws_size,
                              hipStream_t stream)
{
    const float* x  = (const float*)d_in[0];
    const float* cw = (const float*)d_in[1];
    const float* cb = (const float*)d_in[2];
    // d_in[3] (qparams) provably does not affect the output.
    float* out = (float*)d_out;

    const int grid  = BATCH * RG;   // 2048 blocks
    const int block = 256;
    conv_enh_lds<<<grid, block, 0, stream>>>(x, cw, cb, out);
}